// Round 3
// baseline (80.579 us; speedup 1.0000x reference)
//
#include <hip/hip_runtime.h>
#include <hip/hip_cooperative_groups.h>

namespace cg = cooperative_groups;

#define BATCH 64
#define NGT 8
#define DIMT 10647
#define NCLS 20
#define EPS16 6.103515625e-05f

// ws layout (doubles):
//   [b*8 + 0..6]   per-image match partials, b in [0,64)
//   [512 + j]      confsum partial of conf-block j, j in [0,NCB)
// Every slot that is read is written unconditionally each call -> no init.
#define WS_CONF_OFF 512
#define NCB 192                  // confsum blocks
#define GRID_TOT (BATCH + NCB)   // 256 blocks -> 1 block/CU, trivially co-resident

__global__ __launch_bounds__(256) void fused_all(const float* __restrict__ pconf,
                                                 const float* __restrict__ pcls,
                                                 const float* __restrict__ ptxywh,
                                                 const float* __restrict__ gboxes,
                                                 const int* __restrict__ glabels,
                                                 double* __restrict__ ws,
                                                 float* __restrict__ out)
{
    const int t = threadIdx.x;

    __shared__ int   s_base[NGT][3];
    __shared__ float s_txyx[NGT][3], s_txyy[NGT][3];
    __shared__ float s_w[NGT], s_h[NGT], s_wt[NGT];
    __shared__ int   s_lab[NGT], s_ids[NGT];
    __shared__ int   s_cand[72];
    __shared__ float red[4][7];
    __shared__ float lds1[4];
    __shared__ double lds2[4];

    const float ax[9] = {0.025f, 0.04f, 0.08f, 0.07f, 0.15f, 0.14f, 0.28f, 0.38f, 0.9f};
    const float ay[9] = {0.033f, 0.07f, 0.06f, 0.15f, 0.11f, 0.29f, 0.22f, 0.48f, 0.78f};

    if (blockIdx.x >= BATCH) {
        // ---------------- confsum role: sum sigmoid(pconf)^2 ----------------
        const int cb = blockIdx.x - BATCH;      // 0..NCB-1
        const int n4 = (BATCH * DIMT) / 4;      // 170352, exact
        const float4* p4 = reinterpret_cast<const float4*>(pconf);
        float acc = 0.0f;
        for (int i = cb * 256 + t; i < n4; i += NCB * 256) {
            float4 v = p4[i];
            float s0 = 1.0f / (1.0f + expf(-v.x));
            float s1 = 1.0f / (1.0f + expf(-v.y));
            float s2 = 1.0f / (1.0f + expf(-v.z));
            float s3 = 1.0f / (1.0f + expf(-v.w));
            acc += s0 * s0 + s1 * s1 + s2 * s2 + s3 * s3;
        }
        for (int off = 32; off > 0; off >>= 1) acc += __shfl_down(acc, off);
        int wid = t >> 6, lane = t & 63;
        if (lane == 0) lds1[wid] = acc;
        __syncthreads();
        if (t == 0) ws[WS_CONF_OFF + cb] = (double)(lds1[0] + lds1[1] + lds1[2] + lds1[3]);
    } else {
        // ------------------- match role: one image per block -------------------
        const int b = blockIdx.x;
        const int grids[3] = {52, 26, 13};
        const int coff[3]  = {0, 2704, 3380};

        if (t < NGT) {
            int i = t;
            float l  = gboxes[(b * NGT + i) * 4 + 0];
            float tp = gboxes[(b * NGT + i) * 4 + 1];
            float r  = gboxes[(b * NGT + i) * 4 + 2];
            float bt = gboxes[(b * NGT + i) * 4 + 3];
            float cx = (l + r) * 0.5f, cy = (tp + bt) * 0.5f;
            float w = r - l, h = bt - tp;
            s_w[i] = w; s_h[i] = h; s_wt[i] = 2.0f - w * h;
            s_lab[i] = glabels[b * NGT + i] - 1;
            float whp = w * h;
            float best = -1.0f; int bi = 0;
            for (int a = 0; a < 9; a++) {
                float inter = fminf(w, ax[a]) * fminf(h, ay[a]);
                float iou = inter / (whp + ax[a] * ay[a] - inter);
                if (iou > best) { best = iou; bi = a; }
            }
            s_ids[i] = bi;
            for (int s = 0; s < 3; s++) {
                float gf = (float)grids[s];
                int col = (int)(cx * gf);
                int row = (int)(cy * gf);
                s_base[i][s] = (coff[s] + row * grids[s] + col) * 3;
                s_txyx[i][s] = (cx - (float)col / gf) * gf;
                s_txyy[i][s] = (cy - (float)row / gf) * gf;
            }
        }
        __syncthreads();

        if (t < 72) {
            int i = t / 9, r = t % 9;
            s_cand[t] = s_base[i][r / 3] + (r % 3);
        }
        __syncthreads();

        float np_loc = 0.f, naff_loc = 0.f, bsig_loc = 0.f, cpos_loc = 0.f;
        float cls_loc = 0.f, txty_loc = 0.f, twth_loc = 0.f;

        if (t < 72) {
            int d = s_cand[t];
            // dedupe (canonical = first slot with this d) + last neg-writing box
            bool canon = true;
            int lastneg_i = -1;
            for (int v = 0; v < 72; ++v) {
                if (s_cand[v] == d) {
                    if (v < t) canon = false;
                    int iv = v / 9;
                    if (iv > lastneg_i) lastneg_i = iv;
                }
            }
            if (canon) {
                naff_loc = 1.0f;
                int negtag = lastneg_i * 16 + 14;   // last neg write: step (i, j=7), tag 2k
                // pos events (i,j): pos_idx = base[i][ceng[j]] + ancoff[j], tag 2k+1
                int best_tag = -1, bi = -1, bj = -1;
                for (int i = 0; i < NGT; i++) {
                    for (int j = 0; j < NGT; j++) {
                        int s = s_ids[j] / 3, a = s_ids[j] % 3;
                        int pd = s_base[i][s] + a;
                        if (pd == d) {
                            int tag = i * 16 + j * 2 + 1;
                            if (tag > best_tag) { best_tag = tag; bi = i; bj = j; }
                        }
                    }
                }
                float pc = pconf[b * DIMT + d];
                float sg = 1.0f / (1.0f + expf(-pc));
                bsig_loc = sg * sg;
                if (best_tag > negtag) {
                    // final state: pos row written by event (bi, bj)
                    np_loc = 1.0f;
                    cpos_loc = (sg - 1.0f) * (sg - 1.0f);
                    int lab = s_lab[bi];
                    float wt = s_wt[bi];
                    int aidx = s_ids[bj];
                    int s = aidx / 3;
                    float tx = s_txyx[bi][s], ty = s_txyy[bi][s];
                    float twx = logf(s_w[bi] / ax[aidx]);
                    float twy = logf(s_h[bi] / ay[aidx]);
                    const float* pc20 = &pcls[(size_t)(b * DIMT + d) * NCLS];
                    float cs = 0.0f;
                    for (int c = 0; c < NCLS; c++) {
                        float x = pc20[c];
                        float tt = (c == lab) ? 1.0f : 0.0f;
                        cs += fmaxf(x, 0.0f) - x * tt + log1pf(expf(-fabsf(x)));
                    }
                    cls_loc = cs;
                    const float* pt = &ptxywh[(size_t)(b * DIMT + d) * 4];
                    float x0 = pt[0], x1 = pt[1];
                    float bce0 = fmaxf(x0, 0.0f) - x0 * tx + log1pf(expf(-fabsf(x0)));
                    float bce1 = fmaxf(x1, 0.0f) - x1 * ty + log1pf(expf(-fabsf(x1)));
                    txty_loc = (bce0 + bce1) * wt;
                    float d2 = (pt[2] - twx) * (pt[2] - twx) + (pt[3] - twy) * (pt[3] - twy);
                    twth_loc = d2 * wt;
                }
            }
        }

        // block reduce 7 floats
        for (int off = 32; off > 0; off >>= 1) {
            np_loc   += __shfl_down(np_loc, off);
            naff_loc += __shfl_down(naff_loc, off);
            bsig_loc += __shfl_down(bsig_loc, off);
            cpos_loc += __shfl_down(cpos_loc, off);
            cls_loc  += __shfl_down(cls_loc, off);
            txty_loc += __shfl_down(txty_loc, off);
            twth_loc += __shfl_down(twth_loc, off);
        }
        {
            int wid = t >> 6, lane = t & 63;
            if (lane == 0) {
                red[wid][0] = bsig_loc; red[wid][1] = cpos_loc; red[wid][2] = np_loc;
                red[wid][3] = naff_loc; red[wid][4] = cls_loc;  red[wid][5] = txty_loc;
                red[wid][6] = twth_loc;
            }
        }
        __syncthreads();
        if (t == 0) {
            float v[7];
            for (int k = 0; k < 7; k++) v[k] = red[0][k] + red[1][k] + red[2][k] + red[3][k];
            float npos_c = fmaxf(v[2], EPS16);
            ws[b * 8 + 0] = (double)v[0];
            ws[b * 8 + 1] = (double)v[1];
            ws[b * 8 + 2] = (double)v[2];
            ws[b * 8 + 3] = (double)v[3];
            ws[b * 8 + 4] = (double)(v[4] / npos_c);
            ws[b * 8 + 5] = (double)(v[5] / npos_c);
            ws[b * 8 + 6] = (double)(v[6] / npos_c);
        }
    }

    // ---------------- grid-wide barrier, then block 0 combines ----------------
    __threadfence();
    cg::this_grid().sync();

    if (blockIdx.x == 0) {
        // reduce NCB conf partials (threads 0..NCB-1 active, NCB=192 -> waves 0..2)
        double a = (t < NCB) ? ws[WS_CONF_OFF + t] : 0.0;
        for (int off = 32; off > 0; off >>= 1) a += __shfl_down(a, off);
        if ((t & 63) == 0) lds2[t >> 6] = a;
        __syncthreads();

        double v0 = 0, v1 = 0, v2 = 0, v3 = 0, v4 = 0, v5 = 0, v6 = 0;
        if (t < 64) {
            v0 = ws[t * 8 + 0]; v1 = ws[t * 8 + 1]; v2 = ws[t * 8 + 2];
            v3 = ws[t * 8 + 3]; v4 = ws[t * 8 + 4]; v5 = ws[t * 8 + 5];
            v6 = ws[t * 8 + 6];
            for (int off = 32; off > 0; off >>= 1) {
                v0 += __shfl_down(v0, off); v1 += __shfl_down(v1, off);
                v2 += __shfl_down(v2, off); v3 += __shfl_down(v3, off);
                v4 += __shfl_down(v4, off); v5 += __shfl_down(v5, off);
                v6 += __shfl_down(v6, off);
            }
        }
        if (t == 0) {
            double A = lds2[0] + lds2[1] + lds2[2] + lds2[3];
            double tot = (double)BATCH * (double)DIMT;
            double lcp  = v1 / fmax(v2, (double)EPS16) * 30.0;
            double lcn  = (A - v0) / fmax(tot - v3, (double)EPS16) * 30.0;
            double lcls  = v4 / (double)BATCH;
            double ltxty = v5 / (double)BATCH;
            double ltwth = v6 / (double)BATCH;
            out[0] = (float)(lcp + lcn + lcls + ltxty + ltwth);
        }
    }
}

extern "C" void kernel_launch(void* const* d_in, const int* in_sizes, int n_in,
                              void* d_out, int out_size, void* d_ws, size_t ws_size,
                              hipStream_t stream)
{
    const float* pconf = (const float*)d_in[0];
    const float* pcls  = (const float*)d_in[1];
    const float* ptxy  = (const float*)d_in[2];
    const float* gbox  = (const float*)d_in[3];
    const int*   glab  = (const int*)d_in[4];
    double* ws = (double*)d_ws;
    float* outp = (float*)d_out;

    void* args[] = {(void*)&pconf, (void*)&pcls, (void*)&ptxy, (void*)&gbox,
                    (void*)&glab, (void*)&ws, (void*)&outp};
    hipLaunchCooperativeKernel((const void*)fused_all, dim3(GRID_TOT), dim3(256),
                               args, 0, stream);
}

// Round 4
// 28.053 us; speedup vs baseline: 2.8724x; 2.8724x over previous
//
#include <hip/hip_runtime.h>

#define BATCH 64
#define NGT 8
#define DIMT 10647
#define NCLS 20
#define EPS16 6.103515625e-05f

// ws layout:
//   doubles [b*8 + 0..6]  per-image match partials, b in [0,64)
//   doubles [512 + j]     confsum partial of conf-block j, j in [0,NCB)
//   ULL     [768 + k]     done-flag of block k, k in [1,256)
// Partials are written unconditionally every call. Flags are spin-checked
// against MAGIC and reset to 0 by block 0 at the end of every call, so the
// scheme is correct for ANY initial flag value != MAGIC (incl. 0xAA poison).
#define WS_CONF_OFF 512
#define WS_FLAG_OFF 768
#define NCB 192                  // confsum blocks
#define GRID_TOT (BATCH + NCB)   // 256 blocks -> 1 block/CU, all co-resident
#define MAGIC 0x1B5E6F7A9C3D2E4FULL

__global__ __launch_bounds__(256) void fused_spin(const float* __restrict__ pconf,
                                                  const float* __restrict__ pcls,
                                                  const float* __restrict__ ptxywh,
                                                  const float* __restrict__ gboxes,
                                                  const int* __restrict__ glabels,
                                                  double* __restrict__ ws,
                                                  float* __restrict__ out)
{
    const int t = threadIdx.x;
    unsigned long long* flags = reinterpret_cast<unsigned long long*>(ws) + WS_FLAG_OFF;

    __shared__ int   s_base[NGT][3];
    __shared__ float s_txyx[NGT][3], s_txyy[NGT][3];
    __shared__ float s_w[NGT], s_h[NGT], s_wt[NGT];
    __shared__ int   s_lab[NGT], s_ids[NGT];
    __shared__ int   s_cand[72];
    __shared__ float red[4][7];
    __shared__ float lds1[4];
    __shared__ double lds2[4];

    const float ax[9] = {0.025f, 0.04f, 0.08f, 0.07f, 0.15f, 0.14f, 0.28f, 0.38f, 0.9f};
    const float ay[9] = {0.033f, 0.07f, 0.06f, 0.15f, 0.11f, 0.29f, 0.22f, 0.48f, 0.78f};

    if (blockIdx.x >= BATCH) {
        // ---------------- confsum role: sum sigmoid(pconf)^2 ----------------
        const int cb = blockIdx.x - BATCH;      // 0..NCB-1
        const int n4 = (BATCH * DIMT) / 4;      // 170352, exact
        const float4* p4 = reinterpret_cast<const float4*>(pconf);
        float acc = 0.0f;
        for (int i = cb * 256 + t; i < n4; i += NCB * 256) {
            float4 v = p4[i];
            float s0 = 1.0f / (1.0f + expf(-v.x));
            float s1 = 1.0f / (1.0f + expf(-v.y));
            float s2 = 1.0f / (1.0f + expf(-v.z));
            float s3 = 1.0f / (1.0f + expf(-v.w));
            acc += s0 * s0 + s1 * s1 + s2 * s2 + s3 * s3;
        }
        for (int off = 32; off > 0; off >>= 1) acc += __shfl_down(acc, off);
        int wid = t >> 6, lane = t & 63;
        if (lane == 0) lds1[wid] = acc;
        __syncthreads();
        if (t == 0) {
            ws[WS_CONF_OFF + cb] = (double)(lds1[0] + lds1[1] + lds1[2] + lds1[3]);
            __threadfence();   // agent-scope: partial visible before flag
            __hip_atomic_store(&flags[blockIdx.x], MAGIC,
                               __ATOMIC_RELAXED, __HIP_MEMORY_SCOPE_AGENT);
        }
        return;
    }

    // ------------------- match role: one image per block -------------------
    const int b = blockIdx.x;
    {
        const int grids[3] = {52, 26, 13};
        const int coff[3]  = {0, 2704, 3380};

        if (t < NGT) {
            int i = t;
            float l  = gboxes[(b * NGT + i) * 4 + 0];
            float tp = gboxes[(b * NGT + i) * 4 + 1];
            float r  = gboxes[(b * NGT + i) * 4 + 2];
            float bt = gboxes[(b * NGT + i) * 4 + 3];
            float cx = (l + r) * 0.5f, cy = (tp + bt) * 0.5f;
            float w = r - l, h = bt - tp;
            s_w[i] = w; s_h[i] = h; s_wt[i] = 2.0f - w * h;
            s_lab[i] = glabels[b * NGT + i] - 1;
            float whp = w * h;
            float best = -1.0f; int bi = 0;
            for (int a = 0; a < 9; a++) {
                float inter = fminf(w, ax[a]) * fminf(h, ay[a]);
                float iou = inter / (whp + ax[a] * ay[a] - inter);
                if (iou > best) { best = iou; bi = a; }
            }
            s_ids[i] = bi;
            for (int s = 0; s < 3; s++) {
                float gf = (float)grids[s];
                int col = (int)(cx * gf);
                int row = (int)(cy * gf);
                s_base[i][s] = (coff[s] + row * grids[s] + col) * 3;
                s_txyx[i][s] = (cx - (float)col / gf) * gf;
                s_txyy[i][s] = (cy - (float)row / gf) * gf;
            }
        }
        __syncthreads();

        if (t < 72) {
            int i = t / 9, r = t % 9;
            s_cand[t] = s_base[i][r / 3] + (r % 3);
        }
        __syncthreads();

        float np_loc = 0.f, naff_loc = 0.f, bsig_loc = 0.f, cpos_loc = 0.f;
        float cls_loc = 0.f, txty_loc = 0.f, twth_loc = 0.f;

        if (t < 72) {
            int d = s_cand[t];
            // dedupe (canonical = first slot with this d) + last neg-writing box
            bool canon = true;
            int lastneg_i = -1;
            for (int v = 0; v < 72; ++v) {
                if (s_cand[v] == d) {
                    if (v < t) canon = false;
                    int iv = v / 9;
                    if (iv > lastneg_i) lastneg_i = iv;
                }
            }
            if (canon) {
                naff_loc = 1.0f;
                int negtag = lastneg_i * 16 + 14;   // last neg write: step (i, j=7)
                int best_tag = -1, bi = -1, bj = -1;
                for (int i = 0; i < NGT; i++) {
                    for (int j = 0; j < NGT; j++) {
                        int s = s_ids[j] / 3, a = s_ids[j] % 3;
                        int pd = s_base[i][s] + a;
                        if (pd == d) {
                            int tag = i * 16 + j * 2 + 1;
                            if (tag > best_tag) { best_tag = tag; bi = i; bj = j; }
                        }
                    }
                }
                float pc = pconf[b * DIMT + d];
                float sg = 1.0f / (1.0f + expf(-pc));
                bsig_loc = sg * sg;
                if (best_tag > negtag) {
                    np_loc = 1.0f;
                    cpos_loc = (sg - 1.0f) * (sg - 1.0f);
                    int lab = s_lab[bi];
                    float wt = s_wt[bi];
                    int aidx = s_ids[bj];
                    int s = aidx / 3;
                    float tx = s_txyx[bi][s], ty = s_txyy[bi][s];
                    float twx = logf(s_w[bi] / ax[aidx]);
                    float twy = logf(s_h[bi] / ay[aidx]);
                    const float* pc20 = &pcls[(size_t)(b * DIMT + d) * NCLS];
                    float cs = 0.0f;
                    for (int c = 0; c < NCLS; c++) {
                        float x = pc20[c];
                        float tt = (c == lab) ? 1.0f : 0.0f;
                        cs += fmaxf(x, 0.0f) - x * tt + log1pf(expf(-fabsf(x)));
                    }
                    cls_loc = cs;
                    const float* pt = &ptxywh[(size_t)(b * DIMT + d) * 4];
                    float x0 = pt[0], x1 = pt[1];
                    float bce0 = fmaxf(x0, 0.0f) - x0 * tx + log1pf(expf(-fabsf(x0)));
                    float bce1 = fmaxf(x1, 0.0f) - x1 * ty + log1pf(expf(-fabsf(x1)));
                    txty_loc = (bce0 + bce1) * wt;
                    float d2 = (pt[2] - twx) * (pt[2] - twx) + (pt[3] - twy) * (pt[3] - twy);
                    twth_loc = d2 * wt;
                }
            }
        }

        for (int off = 32; off > 0; off >>= 1) {
            np_loc   += __shfl_down(np_loc, off);
            naff_loc += __shfl_down(naff_loc, off);
            bsig_loc += __shfl_down(bsig_loc, off);
            cpos_loc += __shfl_down(cpos_loc, off);
            cls_loc  += __shfl_down(cls_loc, off);
            txty_loc += __shfl_down(txty_loc, off);
            twth_loc += __shfl_down(twth_loc, off);
        }
        {
            int wid = t >> 6, lane = t & 63;
            if (lane == 0) {
                red[wid][0] = bsig_loc; red[wid][1] = cpos_loc; red[wid][2] = np_loc;
                red[wid][3] = naff_loc; red[wid][4] = cls_loc;  red[wid][5] = txty_loc;
                red[wid][6] = twth_loc;
            }
        }
        __syncthreads();
        if (t == 0) {
            float v[7];
            for (int k = 0; k < 7; k++) v[k] = red[0][k] + red[1][k] + red[2][k] + red[3][k];
            float npos_c = fmaxf(v[2], EPS16);
            ws[b * 8 + 0] = (double)v[0];
            ws[b * 8 + 1] = (double)v[1];
            ws[b * 8 + 2] = (double)v[2];
            ws[b * 8 + 3] = (double)v[3];
            ws[b * 8 + 4] = (double)(v[4] / npos_c);
            ws[b * 8 + 5] = (double)(v[5] / npos_c);
            ws[b * 8 + 6] = (double)(v[6] / npos_c);
            if (b != 0) {
                __threadfence();   // partials visible before flag
                __hip_atomic_store(&flags[b], MAGIC,
                                   __ATOMIC_RELAXED, __HIP_MEMORY_SCOPE_AGENT);
            }
        }
        if (b != 0) return;
    }

    // ---------------- block 0: spin on 255 flags, then combine ----------------
    if (t >= 1) {   // thread t waits for block t
        while (__hip_atomic_load(&flags[t], __ATOMIC_RELAXED,
                                 __HIP_MEMORY_SCOPE_AGENT) != MAGIC) {
            __builtin_amdgcn_s_sleep(1);
        }
    }
    __syncthreads();
    __threadfence();   // acquire-fence pairing with writers' release fences

    // reset flags for the next replay (self-restoring state)
    if (t >= 1) {
        __hip_atomic_store(&flags[t], 0ULL, __ATOMIC_RELAXED,
                           __HIP_MEMORY_SCOPE_AGENT);
    }

    // reduce NCB conf partials (threads 0..191)
    double a = (t < NCB) ? ws[WS_CONF_OFF + t] : 0.0;
    for (int off = 32; off > 0; off >>= 1) a += __shfl_down(a, off);
    if ((t & 63) == 0) lds2[t >> 6] = a;
    __syncthreads();

    double v0 = 0, v1 = 0, v2 = 0, v3 = 0, v4 = 0, v5 = 0, v6 = 0;
    if (t < 64) {
        v0 = ws[t * 8 + 0]; v1 = ws[t * 8 + 1]; v2 = ws[t * 8 + 2];
        v3 = ws[t * 8 + 3]; v4 = ws[t * 8 + 4]; v5 = ws[t * 8 + 5];
        v6 = ws[t * 8 + 6];
        for (int off = 32; off > 0; off >>= 1) {
            v0 += __shfl_down(v0, off); v1 += __shfl_down(v1, off);
            v2 += __shfl_down(v2, off); v3 += __shfl_down(v3, off);
            v4 += __shfl_down(v4, off); v5 += __shfl_down(v5, off);
            v6 += __shfl_down(v6, off);
        }
    }
    if (t == 0) {
        double A = lds2[0] + lds2[1] + lds2[2] + lds2[3];
        double tot = (double)BATCH * (double)DIMT;
        double lcp  = v1 / fmax(v2, (double)EPS16) * 30.0;
        double lcn  = (A - v0) / fmax(tot - v3, (double)EPS16) * 30.0;
        double lcls  = v4 / (double)BATCH;
        double ltxty = v5 / (double)BATCH;
        double ltwth = v6 / (double)BATCH;
        out[0] = (float)(lcp + lcn + lcls + ltxty + ltwth);
    }
}

extern "C" void kernel_launch(void* const* d_in, const int* in_sizes, int n_in,
                              void* d_out, int out_size, void* d_ws, size_t ws_size,
                              hipStream_t stream)
{
    const float* pconf = (const float*)d_in[0];
    const float* pcls  = (const float*)d_in[1];
    const float* ptxy  = (const float*)d_in[2];
    const float* gbox  = (const float*)d_in[3];
    const int*   glab  = (const int*)d_in[4];

    fused_spin<<<GRID_TOT, 256, 0, stream>>>(pconf, pcls, ptxy, gbox, glab,
                                             (double*)d_ws, (float*)d_out);
}

// Round 5
// 26.206 us; speedup vs baseline: 3.0748x; 1.0705x over previous
//
#include <hip/hip_runtime.h>

#define BATCH 64
#define NGT 8
#define DIMT 10647
#define NCLS 20
#define EPS16 6.103515625e-05f

// ws layout (8-byte slots):
//   double [b*8 + 0..6]  per-image match partials, b in [0,64)
//   double [512 + j]     confsum partial of conf-block j, j in [0,NCB)
//   ULL    [768 + k]     done-flag of block k, k in [1,256)
// All partials written via agent-scope atomics (LLC-coherent) every call.
// Flags compared against MAGIC and reset to 0 by block 0 each call, so the
// scheme is correct for ANY initial flag value != MAGIC (incl. 0xAA poison).
#define WS_CONF_OFF 512
#define WS_FLAG_OFF 768
#define NCB 192                  // confsum blocks
#define GRID_TOT (BATCH + NCB)   // 256 blocks -> 1 block/CU, all co-resident
#define MAGIC 0x1B5E6F7A9C3D2E4FULL

__device__ __forceinline__ void st_agent(double* p, double v) {
    __hip_atomic_store(p, v, __ATOMIC_RELAXED, __HIP_MEMORY_SCOPE_AGENT);
}
__device__ __forceinline__ double ld_agent(const double* p) {
    return __hip_atomic_load(p, __ATOMIC_RELAXED, __HIP_MEMORY_SCOPE_AGENT);
}

__global__ __launch_bounds__(256) void fused_spin(const float* __restrict__ pconf,
                                                  const float* __restrict__ pcls,
                                                  const float* __restrict__ ptxywh,
                                                  const float* __restrict__ gboxes,
                                                  const int* __restrict__ glabels,
                                                  double* __restrict__ ws,
                                                  float* __restrict__ out)
{
    const int t = threadIdx.x;
    unsigned long long* flags = reinterpret_cast<unsigned long long*>(ws) + WS_FLAG_OFF;

    __shared__ int   s_base[NGT][3];
    __shared__ float s_txyx[NGT][3], s_txyy[NGT][3];
    __shared__ float s_w[NGT], s_h[NGT], s_wt[NGT];
    __shared__ int   s_lab[NGT], s_ids[NGT];
    __shared__ int   s_cand[72];
    __shared__ float red[4][7];
    __shared__ float lds1[4];
    __shared__ double lds2[4];

    const float ax[9] = {0.025f, 0.04f, 0.08f, 0.07f, 0.15f, 0.14f, 0.28f, 0.38f, 0.9f};
    const float ay[9] = {0.033f, 0.07f, 0.06f, 0.15f, 0.11f, 0.29f, 0.22f, 0.48f, 0.78f};

    if (blockIdx.x >= BATCH) {
        // ---------------- confsum role: sum sigmoid(pconf)^2 ----------------
        const int cb = blockIdx.x - BATCH;      // 0..NCB-1
        const int n4 = (BATCH * DIMT) / 4;      // 170352, exact
        const float4* p4 = reinterpret_cast<const float4*>(pconf);
        float acc = 0.0f;
        for (int i = cb * 256 + t; i < n4; i += NCB * 256) {
            float4 v = p4[i];
            float s0 = 1.0f / (1.0f + expf(-v.x));
            float s1 = 1.0f / (1.0f + expf(-v.y));
            float s2 = 1.0f / (1.0f + expf(-v.z));
            float s3 = 1.0f / (1.0f + expf(-v.w));
            acc += s0 * s0 + s1 * s1 + s2 * s2 + s3 * s3;
        }
        for (int off = 32; off > 0; off >>= 1) acc += __shfl_down(acc, off);
        int wid = t >> 6, lane = t & 63;
        if (lane == 0) lds1[wid] = acc;
        __syncthreads();
        if (t == 0) {
            st_agent(&ws[WS_CONF_OFF + cb],
                     (double)(lds1[0] + lds1[1] + lds1[2] + lds1[3]));
            // RELEASE: orders the partial store (vmcnt drain) before the flag;
            // both are agent-scope (LLC) stores -> no L2 writeback fence needed.
            __hip_atomic_store(&flags[blockIdx.x], MAGIC,
                               __ATOMIC_RELEASE, __HIP_MEMORY_SCOPE_AGENT);
        }
        return;
    }

    // ------------------- match role: one image per block -------------------
    const int b = blockIdx.x;
    {
        const int grids[3] = {52, 26, 13};
        const int coff[3]  = {0, 2704, 3380};

        if (t < NGT) {
            int i = t;
            float l  = gboxes[(b * NGT + i) * 4 + 0];
            float tp = gboxes[(b * NGT + i) * 4 + 1];
            float r  = gboxes[(b * NGT + i) * 4 + 2];
            float bt = gboxes[(b * NGT + i) * 4 + 3];
            float cx = (l + r) * 0.5f, cy = (tp + bt) * 0.5f;
            float w = r - l, h = bt - tp;
            s_w[i] = w; s_h[i] = h; s_wt[i] = 2.0f - w * h;
            s_lab[i] = glabels[b * NGT + i] - 1;
            float whp = w * h;
            float best = -1.0f; int bi = 0;
            for (int a = 0; a < 9; a++) {
                float inter = fminf(w, ax[a]) * fminf(h, ay[a]);
                float iou = inter / (whp + ax[a] * ay[a] - inter);
                if (iou > best) { best = iou; bi = a; }
            }
            s_ids[i] = bi;
            for (int s = 0; s < 3; s++) {
                float gf = (float)grids[s];
                int col = (int)(cx * gf);
                int row = (int)(cy * gf);
                s_base[i][s] = (coff[s] + row * grids[s] + col) * 3;
                s_txyx[i][s] = (cx - (float)col / gf) * gf;
                s_txyy[i][s] = (cy - (float)row / gf) * gf;
            }
        }
        __syncthreads();

        if (t < 72) {
            int i = t / 9, r = t % 9;
            s_cand[t] = s_base[i][r / 3] + (r % 3);
        }
        __syncthreads();

        float np_loc = 0.f, naff_loc = 0.f, bsig_loc = 0.f, cpos_loc = 0.f;
        float cls_loc = 0.f, txty_loc = 0.f, twth_loc = 0.f;

        if (t < 72) {
            int d = s_cand[t];
            // dedupe (canonical = first slot with this d) + last neg-writing box
            bool canon = true;
            int lastneg_i = -1;
            for (int v = 0; v < 72; ++v) {
                if (s_cand[v] == d) {
                    if (v < t) canon = false;
                    int iv = v / 9;
                    if (iv > lastneg_i) lastneg_i = iv;
                }
            }
            if (canon) {
                naff_loc = 1.0f;
                int negtag = lastneg_i * 16 + 14;   // last neg write: step (i, j=7)
                int best_tag = -1, bi = -1, bj = -1;
                for (int i = 0; i < NGT; i++) {
                    for (int j = 0; j < NGT; j++) {
                        int s = s_ids[j] / 3, a = s_ids[j] % 3;
                        int pd = s_base[i][s] + a;
                        if (pd == d) {
                            int tag = i * 16 + j * 2 + 1;
                            if (tag > best_tag) { best_tag = tag; bi = i; bj = j; }
                        }
                    }
                }
                float pc = pconf[b * DIMT + d];
                float sg = 1.0f / (1.0f + expf(-pc));
                bsig_loc = sg * sg;
                if (best_tag > negtag) {
                    np_loc = 1.0f;
                    cpos_loc = (sg - 1.0f) * (sg - 1.0f);
                    int lab = s_lab[bi];
                    float wt = s_wt[bi];
                    int aidx = s_ids[bj];
                    int s = aidx / 3;
                    float tx = s_txyx[bi][s], ty = s_txyy[bi][s];
                    float twx = logf(s_w[bi] / ax[aidx]);
                    float twy = logf(s_h[bi] / ay[aidx]);
                    const float* pc20 = &pcls[(size_t)(b * DIMT + d) * NCLS];
                    float cs = 0.0f;
                    for (int c = 0; c < NCLS; c++) {
                        float x = pc20[c];
                        float tt = (c == lab) ? 1.0f : 0.0f;
                        cs += fmaxf(x, 0.0f) - x * tt + log1pf(expf(-fabsf(x)));
                    }
                    cls_loc = cs;
                    const float* pt = &ptxywh[(size_t)(b * DIMT + d) * 4];
                    float x0 = pt[0], x1 = pt[1];
                    float bce0 = fmaxf(x0, 0.0f) - x0 * tx + log1pf(expf(-fabsf(x0)));
                    float bce1 = fmaxf(x1, 0.0f) - x1 * ty + log1pf(expf(-fabsf(x1)));
                    txty_loc = (bce0 + bce1) * wt;
                    float d2 = (pt[2] - twx) * (pt[2] - twx) + (pt[3] - twy) * (pt[3] - twy);
                    twth_loc = d2 * wt;
                }
            }
        }

        for (int off = 32; off > 0; off >>= 1) {
            np_loc   += __shfl_down(np_loc, off);
            naff_loc += __shfl_down(naff_loc, off);
            bsig_loc += __shfl_down(bsig_loc, off);
            cpos_loc += __shfl_down(cpos_loc, off);
            cls_loc  += __shfl_down(cls_loc, off);
            txty_loc += __shfl_down(txty_loc, off);
            twth_loc += __shfl_down(twth_loc, off);
        }
        {
            int wid = t >> 6, lane = t & 63;
            if (lane == 0) {
                red[wid][0] = bsig_loc; red[wid][1] = cpos_loc; red[wid][2] = np_loc;
                red[wid][3] = naff_loc; red[wid][4] = cls_loc;  red[wid][5] = txty_loc;
                red[wid][6] = twth_loc;
            }
        }
        __syncthreads();
        if (t == 0) {
            float v[7];
            for (int k = 0; k < 7; k++) v[k] = red[0][k] + red[1][k] + red[2][k] + red[3][k];
            float npos_c = fmaxf(v[2], EPS16);
            st_agent(&ws[b * 8 + 0], (double)v[0]);
            st_agent(&ws[b * 8 + 1], (double)v[1]);
            st_agent(&ws[b * 8 + 2], (double)v[2]);
            st_agent(&ws[b * 8 + 3], (double)v[3]);
            st_agent(&ws[b * 8 + 4], (double)(v[4] / npos_c));
            st_agent(&ws[b * 8 + 5], (double)(v[5] / npos_c));
            st_agent(&ws[b * 8 + 6], (double)(v[6] / npos_c));
            if (b != 0) {
                __hip_atomic_store(&flags[b], MAGIC,
                                   __ATOMIC_RELEASE, __HIP_MEMORY_SCOPE_AGENT);
            }
        }
        if (b != 0) return;
    }

    // ---------------- block 0: spin on 255 flags, then combine ----------------
    if (t >= 1) {   // thread t waits for block t
        while (__hip_atomic_load(&flags[t], __ATOMIC_RELAXED,
                                 __HIP_MEMORY_SCOPE_AGENT) != MAGIC) {
            __builtin_amdgcn_s_sleep(1);
        }
    }
    __syncthreads();

    // reset flags for the next replay (self-restoring state)
    if (t >= 1) {
        __hip_atomic_store(&flags[t], 0ULL, __ATOMIC_RELAXED,
                           __HIP_MEMORY_SCOPE_AGENT);
    }

    // reduce NCB conf partials (threads 0..191); agent-scope loads read LLC
    double a = (t < NCB) ? ld_agent(&ws[WS_CONF_OFF + t]) : 0.0;
    for (int off = 32; off > 0; off >>= 1) a += __shfl_down(a, off);
    if ((t & 63) == 0) lds2[t >> 6] = a;
    __syncthreads();

    double v0 = 0, v1 = 0, v2 = 0, v3 = 0, v4 = 0, v5 = 0, v6 = 0;
    if (t < 64) {
        v0 = ld_agent(&ws[t * 8 + 0]); v1 = ld_agent(&ws[t * 8 + 1]);
        v2 = ld_agent(&ws[t * 8 + 2]); v3 = ld_agent(&ws[t * 8 + 3]);
        v4 = ld_agent(&ws[t * 8 + 4]); v5 = ld_agent(&ws[t * 8 + 5]);
        v6 = ld_agent(&ws[t * 8 + 6]);
        for (int off = 32; off > 0; off >>= 1) {
            v0 += __shfl_down(v0, off); v1 += __shfl_down(v1, off);
            v2 += __shfl_down(v2, off); v3 += __shfl_down(v3, off);
            v4 += __shfl_down(v4, off); v5 += __shfl_down(v5, off);
            v6 += __shfl_down(v6, off);
        }
    }
    if (t == 0) {
        double A = lds2[0] + lds2[1] + lds2[2] + lds2[3];
        double tot = (double)BATCH * (double)DIMT;
        double lcp  = v1 / fmax(v2, (double)EPS16) * 30.0;
        double lcn  = (A - v0) / fmax(tot - v3, (double)EPS16) * 30.0;
        double lcls  = v4 / (double)BATCH;
        double ltxty = v5 / (double)BATCH;
        double ltwth = v6 / (double)BATCH;
        out[0] = (float)(lcp + lcn + lcls + ltxty + ltwth);
    }
}

extern "C" void kernel_launch(void* const* d_in, const int* in_sizes, int n_in,
                              void* d_out, int out_size, void* d_ws, size_t ws_size,
                              hipStream_t stream)
{
    const float* pconf = (const float*)d_in[0];
    const float* pcls  = (const float*)d_in[1];
    const float* ptxy  = (const float*)d_in[2];
    const float* gbox  = (const float*)d_in[3];
    const int*   glab  = (const int*)d_in[4];

    fused_spin<<<GRID_TOT, 256, 0, stream>>>(pconf, pcls, ptxy, gbox, glab,
                                             (double*)d_ws, (float*)d_out);
}

// Round 6
// 25.794 us; speedup vs baseline: 3.1239x; 1.0160x over previous
//
#include <hip/hip_runtime.h>

#define BATCH 64
#define NGT 8
#define DIMT 10647
#define NCLS 20
#define EPS16 6.103515625e-05f

// ws layout (8-byte slots):
//   double [b*8 + 0..6]  per-image match partials, b in [0,64)
//   double [512 + j]     confsum partial of conf-block j, j in [0,NCB)
//   ULL    [768 + k]     done-flag of block k, k in [1,256)
// All partials written via agent-scope atomics (LLC-coherent) every call.
// Flags compared against MAGIC and reset to 0 by block 0 each call, so the
// scheme is correct for ANY initial flag value != MAGIC (incl. 0xAA poison).
#define WS_CONF_OFF 512
#define WS_FLAG_OFF 768
#define NCB 192                  // confsum blocks
#define GRID_TOT (BATCH + NCB)   // 256 blocks -> 1 block/CU, all co-resident
#define NTHREADS (GRID_TOT * 256)
#define MAGIC 0x1B5E6F7A9C3D2E4FULL

__device__ __forceinline__ void st_agent(double* p, double v) {
    __hip_atomic_store(p, v, __ATOMIC_RELAXED, __HIP_MEMORY_SCOPE_AGENT);
}
__device__ __forceinline__ double ld_agent(const double* p) {
    return __hip_atomic_load(p, __ATOMIC_RELAXED, __HIP_MEMORY_SCOPE_AGENT);
}
__device__ __forceinline__ float sig2(float x) {
    float s = 1.0f / (1.0f + expf(-x));
    return s * s;
}

__global__ __launch_bounds__(256) void fused_spin(const float* __restrict__ pconf,
                                                  const float* __restrict__ pcls,
                                                  const float* __restrict__ ptxywh,
                                                  const float* __restrict__ gboxes,
                                                  const int* __restrict__ glabels,
                                                  double* __restrict__ ws,
                                                  float* __restrict__ out)
{
    const int t = threadIdx.x;
    unsigned long long* flags = reinterpret_cast<unsigned long long*>(ws) + WS_FLAG_OFF;

    __shared__ int   s_base[NGT][3];
    __shared__ float s_txyx[NGT][3], s_txyy[NGT][3];
    __shared__ float s_w[NGT], s_h[NGT], s_wt[NGT];
    __shared__ int   s_lab[NGT], s_ids[NGT];
    __shared__ int   s_cand[72];
    __shared__ float red[4][7];
    __shared__ float lds1[4];
    __shared__ double lds2[4];

    const float ax[9] = {0.025f, 0.04f, 0.08f, 0.07f, 0.15f, 0.14f, 0.28f, 0.38f, 0.9f};
    const float ay[9] = {0.033f, 0.07f, 0.06f, 0.15f, 0.11f, 0.29f, 0.22f, 0.48f, 0.78f};

    if (blockIdx.x >= BATCH) {
        // ---------------- confsum role: sum sigmoid(pconf)^2 ----------------
        // n4 = 170352 = 3*NTHREADS_conf + rem, NTHREADS_conf = 192*256 = 49152.
        // 3 unconditional iterations + 1 conditional -> 4 loads in flight.
        const int cb = blockIdx.x - BATCH;      // 0..NCB-1
        const int n4 = (BATCH * DIMT) / 4;      // 170352, exact
        const int stride = NCB * 256;           // 49152
        const int i0 = cb * 256 + t;
        const float4* p4 = reinterpret_cast<const float4*>(pconf);
        float4 a0 = p4[i0];
        float4 a1 = p4[i0 + stride];
        float4 a2 = p4[i0 + 2 * stride];
        float4 a3 = (i0 + 3 * stride < n4) ? p4[i0 + 3 * stride]
                                           : make_float4(0.f, 0.f, 0.f, 0.f);
        // sig2(0)=0.25 for padded lanes -> mask instead of branch on compute
        float acc = sig2(a0.x) + sig2(a0.y) + sig2(a0.z) + sig2(a0.w)
                  + sig2(a1.x) + sig2(a1.y) + sig2(a1.z) + sig2(a1.w)
                  + sig2(a2.x) + sig2(a2.y) + sig2(a2.z) + sig2(a2.w);
        if (i0 + 3 * stride < n4)
            acc += sig2(a3.x) + sig2(a3.y) + sig2(a3.z) + sig2(a3.w);
        for (int off = 32; off > 0; off >>= 1) acc += __shfl_down(acc, off);
        int wid = t >> 6, lane = t & 63;
        if (lane == 0) lds1[wid] = acc;
        __syncthreads();
        if (t == 0) {
            st_agent(&ws[WS_CONF_OFF + cb],
                     (double)(lds1[0] + lds1[1] + lds1[2] + lds1[3]));
            // RELEASE: orders the partial store before the flag (both LLC-scope).
            __hip_atomic_store(&flags[blockIdx.x], MAGIC,
                               __ATOMIC_RELEASE, __HIP_MEMORY_SCOPE_AGENT);
        }
        return;
    }

    // ------------------- match role: one image per block -------------------
    const int b = blockIdx.x;
    {
        const int grids[3] = {52, 26, 13};
        const int coff[3]  = {0, 2704, 3380};

        if (t < NGT) {
            int i = t;
            float l  = gboxes[(b * NGT + i) * 4 + 0];
            float tp = gboxes[(b * NGT + i) * 4 + 1];
            float r  = gboxes[(b * NGT + i) * 4 + 2];
            float bt = gboxes[(b * NGT + i) * 4 + 3];
            float cx = (l + r) * 0.5f, cy = (tp + bt) * 0.5f;
            float w = r - l, h = bt - tp;
            s_w[i] = w; s_h[i] = h; s_wt[i] = 2.0f - w * h;
            s_lab[i] = glabels[b * NGT + i] - 1;
            float whp = w * h;
            float best = -1.0f; int bi = 0;
            for (int a = 0; a < 9; a++) {
                float inter = fminf(w, ax[a]) * fminf(h, ay[a]);
                float iou = inter / (whp + ax[a] * ay[a] - inter);
                if (iou > best) { best = iou; bi = a; }
            }
            s_ids[i] = bi;
            for (int s = 0; s < 3; s++) {
                float gf = (float)grids[s];
                int col = (int)(cx * gf);
                int row = (int)(cy * gf);
                s_base[i][s] = (coff[s] + row * grids[s] + col) * 3;
                s_txyx[i][s] = (cx - (float)col / gf) * gf;
                s_txyy[i][s] = (cy - (float)row / gf) * gf;
            }
        }
        __syncthreads();

        if (t < 72) {
            int i = t / 9, r = t % 9;
            s_cand[t] = s_base[i][r / 3] + (r % 3);
        }
        __syncthreads();

        float np_loc = 0.f, naff_loc = 0.f, bsig_loc = 0.f, cpos_loc = 0.f;
        float cls_loc = 0.f, txty_loc = 0.f, twth_loc = 0.f;

        if (t < 72) {
            int d = s_cand[t];
            // dedupe (canonical = first slot with this d) + last neg-writing box
            bool canon = true;
            int lastneg_i = -1;
            for (int v = 0; v < 72; ++v) {
                if (s_cand[v] == d) {
                    if (v < t) canon = false;
                    int iv = v / 9;
                    if (iv > lastneg_i) lastneg_i = iv;
                }
            }
            if (canon) {
                naff_loc = 1.0f;
                int negtag = lastneg_i * 16 + 14;   // last neg write: step (i, j=7)
                int best_tag = -1, bi = -1, bj = -1;
                for (int i = 0; i < NGT; i++) {
                    for (int j = 0; j < NGT; j++) {
                        int s = s_ids[j] / 3, a = s_ids[j] % 3;
                        int pd = s_base[i][s] + a;
                        if (pd == d) {
                            int tag = i * 16 + j * 2 + 1;
                            if (tag > best_tag) { best_tag = tag; bi = i; bj = j; }
                        }
                    }
                }
                float pc = pconf[b * DIMT + d];
                float sg = 1.0f / (1.0f + expf(-pc));
                bsig_loc = sg * sg;
                if (best_tag > negtag) {
                    np_loc = 1.0f;
                    cpos_loc = (sg - 1.0f) * (sg - 1.0f);
                    int lab = s_lab[bi];
                    float wt = s_wt[bi];
                    int aidx = s_ids[bj];
                    int s = aidx / 3;
                    float tx = s_txyx[bi][s], ty = s_txyy[bi][s];
                    float twx = logf(s_w[bi] / ax[aidx]);
                    float twy = logf(s_h[bi] / ay[aidx]);
                    const float* pc20 = &pcls[(size_t)(b * DIMT + d) * NCLS];
                    float cs = 0.0f;
                    for (int c = 0; c < NCLS; c++) {
                        float x = pc20[c];
                        float tt = (c == lab) ? 1.0f : 0.0f;
                        cs += fmaxf(x, 0.0f) - x * tt + log1pf(expf(-fabsf(x)));
                    }
                    cls_loc = cs;
                    const float* pt = &ptxywh[(size_t)(b * DIMT + d) * 4];
                    float x0 = pt[0], x1 = pt[1];
                    float bce0 = fmaxf(x0, 0.0f) - x0 * tx + log1pf(expf(-fabsf(x0)));
                    float bce1 = fmaxf(x1, 0.0f) - x1 * ty + log1pf(expf(-fabsf(x1)));
                    txty_loc = (bce0 + bce1) * wt;
                    float d2 = (pt[2] - twx) * (pt[2] - twx) + (pt[3] - twy) * (pt[3] - twy);
                    twth_loc = d2 * wt;
                }
            }
        }

        for (int off = 32; off > 0; off >>= 1) {
            np_loc   += __shfl_down(np_loc, off);
            naff_loc += __shfl_down(naff_loc, off);
            bsig_loc += __shfl_down(bsig_loc, off);
            cpos_loc += __shfl_down(cpos_loc, off);
            cls_loc  += __shfl_down(cls_loc, off);
            txty_loc += __shfl_down(txty_loc, off);
            twth_loc += __shfl_down(twth_loc, off);
        }
        {
            int wid = t >> 6, lane = t & 63;
            if (lane == 0) {
                red[wid][0] = bsig_loc; red[wid][1] = cpos_loc; red[wid][2] = np_loc;
                red[wid][3] = naff_loc; red[wid][4] = cls_loc;  red[wid][5] = txty_loc;
                red[wid][6] = twth_loc;
            }
        }
        __syncthreads();
        if (t == 0) {
            float v[7];
            for (int k = 0; k < 7; k++) v[k] = red[0][k] + red[1][k] + red[2][k] + red[3][k];
            float npos_c = fmaxf(v[2], EPS16);
            st_agent(&ws[b * 8 + 0], (double)v[0]);
            st_agent(&ws[b * 8 + 1], (double)v[1]);
            st_agent(&ws[b * 8 + 2], (double)v[2]);
            st_agent(&ws[b * 8 + 3], (double)v[3]);
            st_agent(&ws[b * 8 + 4], (double)(v[4] / npos_c));
            st_agent(&ws[b * 8 + 5], (double)(v[5] / npos_c));
            st_agent(&ws[b * 8 + 6], (double)(v[6] / npos_c));
            if (b != 0) {
                __hip_atomic_store(&flags[b], MAGIC,
                                   __ATOMIC_RELEASE, __HIP_MEMORY_SCOPE_AGENT);
            }
        }
        if (b != 0) return;
    }

    // ------- block 0: per-thread wait-and-consume (overlapped), combine -------
    double a = 0.0;                                 // conf partial (threads 64..255)
    double v0 = 0, v1 = 0, v2 = 0, v3 = 0, v4 = 0, v5 = 0, v6 = 0;  // match (0..63)
    if (t >= 64) {
        // thread t consumes conf block cb = t-64, whose blockIdx/flag index == t
        while (__hip_atomic_load(&flags[t], __ATOMIC_RELAXED,
                                 __HIP_MEMORY_SCOPE_AGENT) != MAGIC) {
            __builtin_amdgcn_s_sleep(1);
        }
        a = ld_agent(&ws[WS_CONF_OFF + (t - 64)]);
        __hip_atomic_store(&flags[t], 0ULL, __ATOMIC_RELAXED,
                           __HIP_MEMORY_SCOPE_AGENT);
    } else {
        // thread t consumes match image t (t==0: own block's partials, no flag)
        if (t >= 1) {
            while (__hip_atomic_load(&flags[t], __ATOMIC_RELAXED,
                                     __HIP_MEMORY_SCOPE_AGENT) != MAGIC) {
                __builtin_amdgcn_s_sleep(1);
            }
        }
        v0 = ld_agent(&ws[t * 8 + 0]); v1 = ld_agent(&ws[t * 8 + 1]);
        v2 = ld_agent(&ws[t * 8 + 2]); v3 = ld_agent(&ws[t * 8 + 3]);
        v4 = ld_agent(&ws[t * 8 + 4]); v5 = ld_agent(&ws[t * 8 + 5]);
        v6 = ld_agent(&ws[t * 8 + 6]);
        if (t >= 1) {
            __hip_atomic_store(&flags[t], 0ULL, __ATOMIC_RELAXED,
                               __HIP_MEMORY_SCOPE_AGENT);
        }
    }

    // conf reduce: waves 1..3 shuffle, lane-0s -> lds2
    if (t >= 64) {
        for (int off = 32; off > 0; off >>= 1) a += __shfl_down(a, off);
        if ((t & 63) == 0) lds2[t >> 6] = a;
    }
    // match reduce: wave 0
    if (t < 64) {
        for (int off = 32; off > 0; off >>= 1) {
            v0 += __shfl_down(v0, off); v1 += __shfl_down(v1, off);
            v2 += __shfl_down(v2, off); v3 += __shfl_down(v3, off);
            v4 += __shfl_down(v4, off); v5 += __shfl_down(v5, off);
            v6 += __shfl_down(v6, off);
        }
    }
    __syncthreads();
    if (t == 0) {
        double A = lds2[1] + lds2[2] + lds2[3];
        double tot = (double)BATCH * (double)DIMT;
        double lcp  = v1 / fmax(v2, (double)EPS16) * 30.0;
        double lcn  = (A - v0) / fmax(tot - v3, (double)EPS16) * 30.0;
        double lcls  = v4 / (double)BATCH;
        double ltxty = v5 / (double)BATCH;
        double ltwth = v6 / (double)BATCH;
        out[0] = (float)(lcp + lcn + lcls + ltxty + ltwth);
    }
}

extern "C" void kernel_launch(void* const* d_in, const int* in_sizes, int n_in,
                              void* d_out, int out_size, void* d_ws, size_t ws_size,
                              hipStream_t stream)
{
    const float* pconf = (const float*)d_in[0];
    const float* pcls  = (const float*)d_in[1];
    const float* ptxy  = (const float*)d_in[2];
    const float* gbox  = (const float*)d_in[3];
    const int*   glab  = (const int*)d_in[4];

    fused_spin<<<GRID_TOT, 256, 0, stream>>>(pconf, pcls, ptxy, gbox, glab,
                                             (double*)d_ws, (float*)d_out);
}

// Round 7
// 25.536 us; speedup vs baseline: 3.1555x; 1.0101x over previous
//
#include <hip/hip_runtime.h>

#define BATCH 64
#define NGT 8
#define DIMT 10647
#define NCLS 20
#define EPS16 6.103515625e-05f

// ws layout (8-byte slots):
//   double [b*8 + 0..6]  per-image match partials, b in [0,64)
//   ULL    [b*8 + 7]     match done-flag (same 64B cacheline as the data)
//   double [512 + j]     confsum partial of conf-block j, j in [0,NCB)
//                        STRICTLY POSITIVE -> the value is its own flag:
//                        poison (0xAA..) is a negative double, reset = 0.0,
//                        so poll (val > 0) is correct for any prior state.
// Block 0 resets conf slots to 0.0 and match flags to 0 each call
// (graph nodes replay serially, so no cross-replay overlap).
#define WS_CONF_OFF 512
#define NCB 192                  // confsum blocks
#define GRID_TOT (BATCH + NCB)   // 256 blocks -> 1 block/CU, all co-resident
#define MAGIC 0x1B5E6F7A9C3D2E4FULL

__device__ __forceinline__ void st_agent(double* p, double v) {
    __hip_atomic_store(p, v, __ATOMIC_RELAXED, __HIP_MEMORY_SCOPE_AGENT);
}
__device__ __forceinline__ double ld_agent(const double* p) {
    return __hip_atomic_load(p, __ATOMIC_RELAXED, __HIP_MEMORY_SCOPE_AGENT);
}
__device__ __forceinline__ float sig2(float x) {
    float s = 1.0f / (1.0f + expf(-x));
    return s * s;
}

__global__ __launch_bounds__(256) void fused_spin(const float* __restrict__ pconf,
                                                  const float* __restrict__ pcls,
                                                  const float* __restrict__ ptxywh,
                                                  const float* __restrict__ gboxes,
                                                  const int* __restrict__ glabels,
                                                  double* __restrict__ ws,
                                                  float* __restrict__ out)
{
    const int t = threadIdx.x;

    __shared__ int   s_base[NGT][3];
    __shared__ float s_txyx[NGT][3], s_txyy[NGT][3];
    __shared__ float s_w[NGT], s_h[NGT], s_wt[NGT];
    __shared__ int   s_lab[NGT], s_ids[NGT];
    __shared__ int   s_cand[72];
    __shared__ float red[4][7];
    __shared__ float lds1[4];
    __shared__ double lds2[4];

    const float ax[9] = {0.025f, 0.04f, 0.08f, 0.07f, 0.15f, 0.14f, 0.28f, 0.38f, 0.9f};
    const float ay[9] = {0.033f, 0.07f, 0.06f, 0.15f, 0.11f, 0.29f, 0.22f, 0.48f, 0.78f};

    if (blockIdx.x >= BATCH) {
        // ---------------- confsum role: sum sigmoid(pconf)^2 ----------------
        const int cb = blockIdx.x - BATCH;      // 0..NCB-1
        const int n4 = (BATCH * DIMT) / 4;      // 170352, exact
        const int stride = NCB * 256;           // 49152
        const int i0 = cb * 256 + t;
        const float4* p4 = reinterpret_cast<const float4*>(pconf);
        float4 a0 = p4[i0];
        float4 a1 = p4[i0 + stride];
        float4 a2 = p4[i0 + 2 * stride];
        float4 a3 = (i0 + 3 * stride < n4) ? p4[i0 + 3 * stride]
                                           : make_float4(0.f, 0.f, 0.f, 0.f);
        float acc = sig2(a0.x) + sig2(a0.y) + sig2(a0.z) + sig2(a0.w)
                  + sig2(a1.x) + sig2(a1.y) + sig2(a1.z) + sig2(a1.w)
                  + sig2(a2.x) + sig2(a2.y) + sig2(a2.z) + sig2(a2.w);
        if (i0 + 3 * stride < n4)
            acc += sig2(a3.x) + sig2(a3.y) + sig2(a3.z) + sig2(a3.w);
        for (int off = 32; off > 0; off >>= 1) acc += __shfl_down(acc, off);
        int wid = t >> 6, lane = t & 63;
        if (lane == 0) lds1[wid] = acc;
        __syncthreads();
        if (t == 0) {
            // Strictly-positive partial IS the completion flag: single relaxed
            // agent-scope (LLC) store, no ordering needed.
            st_agent(&ws[WS_CONF_OFF + cb],
                     (double)(lds1[0] + lds1[1] + lds1[2] + lds1[3]));
        }
        return;
    }

    // ------------------- match role: one image per block -------------------
    const int b = blockIdx.x;
    double my_v0 = 0, my_v1 = 0, my_v2 = 0, my_v3 = 0, my_v4 = 0, my_v5 = 0, my_v6 = 0;
    {
        const int grids[3] = {52, 26, 13};
        const int coff[3]  = {0, 2704, 3380};

        if (t < NGT) {
            int i = t;
            float l  = gboxes[(b * NGT + i) * 4 + 0];
            float tp = gboxes[(b * NGT + i) * 4 + 1];
            float r  = gboxes[(b * NGT + i) * 4 + 2];
            float bt = gboxes[(b * NGT + i) * 4 + 3];
            float cx = (l + r) * 0.5f, cy = (tp + bt) * 0.5f;
            float w = r - l, h = bt - tp;
            s_w[i] = w; s_h[i] = h; s_wt[i] = 2.0f - w * h;
            s_lab[i] = glabels[b * NGT + i] - 1;
            float whp = w * h;
            float best = -1.0f; int bi = 0;
            for (int a = 0; a < 9; a++) {
                float inter = fminf(w, ax[a]) * fminf(h, ay[a]);
                float iou = inter / (whp + ax[a] * ay[a] - inter);
                if (iou > best) { best = iou; bi = a; }
            }
            s_ids[i] = bi;
            for (int s = 0; s < 3; s++) {
                float gf = (float)grids[s];
                int col = (int)(cx * gf);
                int row = (int)(cy * gf);
                s_base[i][s] = (coff[s] + row * grids[s] + col) * 3;
                s_txyx[i][s] = (cx - (float)col / gf) * gf;
                s_txyy[i][s] = (cy - (float)row / gf) * gf;
            }
        }
        __syncthreads();

        if (t < 72) {
            int i = t / 9, r = t % 9;
            s_cand[t] = s_base[i][r / 3] + (r % 3);
        }
        __syncthreads();

        float np_loc = 0.f, naff_loc = 0.f, bsig_loc = 0.f, cpos_loc = 0.f;
        float cls_loc = 0.f, txty_loc = 0.f, twth_loc = 0.f;

        if (t < 72) {
            int d = s_cand[t];
            // dedupe (canonical = first slot with this d) + last neg-writing box
            bool canon = true;
            int lastneg_i = -1;
            for (int v = 0; v < 72; ++v) {
                if (s_cand[v] == d) {
                    if (v < t) canon = false;
                    int iv = v / 9;
                    if (iv > lastneg_i) lastneg_i = iv;
                }
            }
            if (canon) {
                naff_loc = 1.0f;
                int negtag = lastneg_i * 16 + 14;   // last neg write: step (i, j=7)
                int best_tag = -1, bi = -1, bj = -1;
                for (int i = 0; i < NGT; i++) {
                    for (int j = 0; j < NGT; j++) {
                        int s = s_ids[j] / 3, a = s_ids[j] % 3;
                        int pd = s_base[i][s] + a;
                        if (pd == d) {
                            int tag = i * 16 + j * 2 + 1;
                            if (tag > best_tag) { best_tag = tag; bi = i; bj = j; }
                        }
                    }
                }
                float pc = pconf[b * DIMT + d];
                float sg = 1.0f / (1.0f + expf(-pc));
                bsig_loc = sg * sg;
                if (best_tag > negtag) {
                    np_loc = 1.0f;
                    cpos_loc = (sg - 1.0f) * (sg - 1.0f);
                    int lab = s_lab[bi];
                    float wt = s_wt[bi];
                    int aidx = s_ids[bj];
                    int s = aidx / 3;
                    float tx = s_txyx[bi][s], ty = s_txyy[bi][s];
                    float twx = logf(s_w[bi] / ax[aidx]);
                    float twy = logf(s_h[bi] / ay[aidx]);
                    const float* pc20 = &pcls[(size_t)(b * DIMT + d) * NCLS];
                    float cs = 0.0f;
                    for (int c = 0; c < NCLS; c++) {
                        float x = pc20[c];
                        float tt = (c == lab) ? 1.0f : 0.0f;
                        cs += fmaxf(x, 0.0f) - x * tt + log1pf(expf(-fabsf(x)));
                    }
                    cls_loc = cs;
                    const float* pt = &ptxywh[(size_t)(b * DIMT + d) * 4];
                    float x0 = pt[0], x1 = pt[1];
                    float bce0 = fmaxf(x0, 0.0f) - x0 * tx + log1pf(expf(-fabsf(x0)));
                    float bce1 = fmaxf(x1, 0.0f) - x1 * ty + log1pf(expf(-fabsf(x1)));
                    txty_loc = (bce0 + bce1) * wt;
                    float d2 = (pt[2] - twx) * (pt[2] - twx) + (pt[3] - twy) * (pt[3] - twy);
                    twth_loc = d2 * wt;
                }
            }
        }

        for (int off = 32; off > 0; off >>= 1) {
            np_loc   += __shfl_down(np_loc, off);
            naff_loc += __shfl_down(naff_loc, off);
            bsig_loc += __shfl_down(bsig_loc, off);
            cpos_loc += __shfl_down(cpos_loc, off);
            cls_loc  += __shfl_down(cls_loc, off);
            txty_loc += __shfl_down(txty_loc, off);
            twth_loc += __shfl_down(twth_loc, off);
        }
        {
            int wid = t >> 6, lane = t & 63;
            if (lane == 0) {
                red[wid][0] = bsig_loc; red[wid][1] = cpos_loc; red[wid][2] = np_loc;
                red[wid][3] = naff_loc; red[wid][4] = cls_loc;  red[wid][5] = txty_loc;
                red[wid][6] = twth_loc;
            }
        }
        __syncthreads();
        if (t == 0) {
            float v[7];
            for (int k = 0; k < 7; k++) v[k] = red[0][k] + red[1][k] + red[2][k] + red[3][k];
            float npos_c = fmaxf(v[2], EPS16);
            my_v0 = (double)v[0];
            my_v1 = (double)v[1];
            my_v2 = (double)v[2];
            my_v3 = (double)v[3];
            my_v4 = (double)(v[4] / npos_c);
            my_v5 = (double)(v[5] / npos_c);
            my_v6 = (double)(v[6] / npos_c);
            if (b != 0) {
                st_agent(&ws[b * 8 + 0], my_v0);
                st_agent(&ws[b * 8 + 1], my_v1);
                st_agent(&ws[b * 8 + 2], my_v2);
                st_agent(&ws[b * 8 + 3], my_v3);
                st_agent(&ws[b * 8 + 4], my_v4);
                st_agent(&ws[b * 8 + 5], my_v5);
                st_agent(&ws[b * 8 + 6], my_v6);
                // flag lives in the same 64B line; RELEASE orders the 7 stores
                __hip_atomic_store((unsigned long long*)&ws[b * 8 + 7], MAGIC,
                                   __ATOMIC_RELEASE, __HIP_MEMORY_SCOPE_AGENT);
            }
        }
        if (b != 0) return;
    }

    // ------- block 0: per-thread wait-and-consume (overlapped), combine -------
    double a = 0.0;                                 // conf partial (threads 64..255)
    double v0 = 0, v1 = 0, v2 = 0, v3 = 0, v4 = 0, v5 = 0, v6 = 0;  // match (0..63)
    if (t >= 64) {
        // conf channel: the strictly-positive value is its own flag
        double* slot = &ws[WS_CONF_OFF + (t - 64)];
        do {
            a = ld_agent(slot);
            if (a > 0.0) break;
            __builtin_amdgcn_s_sleep(1);
        } while (true);
        st_agent(slot, 0.0);   // reset for next replay
    } else if (t >= 1) {
        unsigned long long* fl = (unsigned long long*)&ws[t * 8 + 7];
        while (__hip_atomic_load(fl, __ATOMIC_RELAXED,
                                 __HIP_MEMORY_SCOPE_AGENT) != MAGIC) {
            __builtin_amdgcn_s_sleep(1);
        }
        v0 = ld_agent(&ws[t * 8 + 0]); v1 = ld_agent(&ws[t * 8 + 1]);
        v2 = ld_agent(&ws[t * 8 + 2]); v3 = ld_agent(&ws[t * 8 + 3]);
        v4 = ld_agent(&ws[t * 8 + 4]); v5 = ld_agent(&ws[t * 8 + 5]);
        v6 = ld_agent(&ws[t * 8 + 6]);
        __hip_atomic_store(fl, 0ULL, __ATOMIC_RELAXED, __HIP_MEMORY_SCOPE_AGENT);
    } else {
        // t == 0: image 0's partials never left registers
        v0 = my_v0; v1 = my_v1; v2 = my_v2; v3 = my_v3;
        v4 = my_v4; v5 = my_v5; v6 = my_v6;
    }

    // conf reduce: waves 1..3 shuffle, lane-0s -> lds2[1..3]
    if (t >= 64) {
        for (int off = 32; off > 0; off >>= 1) a += __shfl_down(a, off);
        if ((t & 63) == 0) lds2[t >> 6] = a;
    }
    // match reduce: wave 0
    if (t < 64) {
        for (int off = 32; off > 0; off >>= 1) {
            v0 += __shfl_down(v0, off); v1 += __shfl_down(v1, off);
            v2 += __shfl_down(v2, off); v3 += __shfl_down(v3, off);
            v4 += __shfl_down(v4, off); v5 += __shfl_down(v5, off);
            v6 += __shfl_down(v6, off);
        }
    }
    __syncthreads();
    if (t == 0) {
        double A = lds2[1] + lds2[2] + lds2[3];
        double tot = (double)BATCH * (double)DIMT;
        double lcp  = v1 / fmax(v2, (double)EPS16) * 30.0;
        double lcn  = (A - v0) / fmax(tot - v3, (double)EPS16) * 30.0;
        double lcls  = v4 / (double)BATCH;
        double ltxty = v5 / (double)BATCH;
        double ltwth = v6 / (double)BATCH;
        out[0] = (float)(lcp + lcn + lcls + ltxty + ltwth);
    }
}

extern "C" void kernel_launch(void* const* d_in, const int* in_sizes, int n_in,
                              void* d_out, int out_size, void* d_ws, size_t ws_size,
                              hipStream_t stream)
{
    const float* pconf = (const float*)d_in[0];
    const float* pcls  = (const float*)d_in[1];
    const float* ptxy  = (const float*)d_in[2];
    const float* gbox  = (const float*)d_in[3];
    const int*   glab  = (const int*)d_in[4];

    fused_spin<<<GRID_TOT, 256, 0, stream>>>(pconf, pcls, ptxy, gbox, glab,
                                             (double*)d_ws, (float*)d_out);
}